// Round 10
// baseline (3511.647 us; speedup 1.0000x reference)
//
#include <hip/hip_runtime.h>

// DRNN: 4-layer dilated LSTM, T=2048, dil {1,2,4,8}, dims 256->128->128->128->256.
//
// Round-10: single-barrier R0. Pipeline: R0 | R1 x2 | R2 x4 | R3 8x4 (XCD-
// claimed, agent-scope peer exchange). Blocks are 320 threads:
//  R0: waves 0-3 = lane-PAIR cells (lane 2m/2m+1 = cell m's 4 gate rows split
//      by k-half; partials merged via 4x shfl_xor -- no LDS z round trip, no
//      second barrier). Wave 4 = zx stager (global->LDS double buffer, depth-2
//      reg prefetch) + ring guard. Compute wave's ONLY vmem op is the fire-and-
//      forget y0 publish => no vmcnt waits can drain system stores.
//  R1/R2/R3: round-8 structure; t>=256 runs a barrier-matched skeleton loop.
// Keepers/burn removed (round 9 refuted DVFS). Cross-block: (tag16<<16)|fp16
// relaxed system-scope; R3 peers agent-scope. Barriers raw s_barrier+lgkmcnt.
// Poison 0xAAAA = negative tag = not ready. All polls budgeted: never hang.

typedef unsigned int u32;
typedef _Float16 h2v __attribute__((ext_vector_type(2)));

#define TSTEPS 2048

// u32 region after zx (float zx[2048*512])
#define ZX_FLOATS 1048576
#define Y0_OFF 0        // 256*128 u32 ring
#define Y1_OFF 32768
#define Y2_OFF 65536
#define HX_OFF 98304    // 256*256 (agent-scope, XCD-local per chain)
#define PROG_OFF 163840 // 8 chains * 64 stride
#define CNT_OFF 164352  // [0..7] XCD claim counters

__device__ __forceinline__ void barL() {
  asm volatile("s_waitcnt lgkmcnt(0)\ns_barrier" ::: "memory");
}
__device__ __forceinline__ float f_sig(float x) { return 1.0f / (1.0f + __expf(-x)); }
__device__ __forceinline__ float f_tanh(float x) {
  float xc = fminf(fmaxf(x, -15.0f), 15.0f);
  float e = __expf(2.0f * xc);
  return (e - 1.0f) / (e + 1.0f);
}
__device__ __forceinline__ u32 pld32(const u32* p) {
  return __hip_atomic_load((u32*)p, __ATOMIC_RELAXED, __HIP_MEMORY_SCOPE_SYSTEM);
}
__device__ __forceinline__ void pst16(u32* p, int j, float v) {
  _Float16 hv = (_Float16)v;
  u32 u = ((u32)(j + 1) << 16) | (u32)__builtin_bit_cast(unsigned short, hv);
  __hip_atomic_store(p, u, __ATOMIC_RELAXED, __HIP_MEMORY_SCOPE_SYSTEM);
}
__device__ __forceinline__ u32 pldA(const u32* p) {
  return __hip_atomic_load((u32*)p, __ATOMIC_RELAXED, __HIP_MEMORY_SCOPE_AGENT);
}
__device__ __forceinline__ void pstA16(u32* p, int j, float v) {
  _Float16 hv = (_Float16)v;
  u32 u = ((u32)(j + 1) << 16) | (u32)__builtin_bit_cast(unsigned short, hv);
  __hip_atomic_store(p, u, __ATOMIC_RELAXED, __HIP_MEMORY_SCOPE_AGENT);
}
__device__ __forceinline__ int ptag16(u32 u) { return (int)(short)(u >> 16); }
__device__ __forceinline__ _Float16 pval16(u32 u) {
  return __builtin_bit_cast(_Float16, (unsigned short)(u & 0xffffu));
}
__device__ __forceinline__ void ensure32(u32& u, const u32* p, int need, int& bud) {
  while (ptag16(u) < need) { if (--bud < 0) break; u = pld32(p); }
}
__device__ __forceinline__ void pollg32(const u32* p, int need, int& bud) {
  u32 g = pld32(p);
  while (ptag16(g) < need) { if (--bud < 0) break; g = pld32(p); }
}

// ---------------- kernel 1: zx[j][r] = Wih0[r,:]@x[j,:] + bih0[r] + bhh0[r] ----
__global__ __launch_bounds__(256) void zx0_kernel(
    const float* __restrict__ x, const float* __restrict__ Wih0,
    const float* __restrict__ bih0, const float* __restrict__ bhh0,
    float* __restrict__ zx) {
  __shared__ float xs[4 * 256];
  const int t = threadIdx.x;
  const int j0 = blockIdx.x * 4;
  ((float4*)xs)[t] = ((const float4*)(x + j0 * 256))[t];
  __syncthreads();
  const int r0 = t, r1 = t + 256;
  float a0[4] = {0, 0, 0, 0}, a1[4] = {0, 0, 0, 0};
  const float* w0p = Wih0 + r0 * 256;
  const float* w1p = Wih0 + r1 * 256;
#pragma unroll 8
  for (int k = 0; k < 256; k += 4) {
    float4 wa = *(const float4*)(w0p + k);
    float4 wb = *(const float4*)(w1p + k);
#pragma unroll
    for (int jj = 0; jj < 4; jj++) {
      float4 xv = *(const float4*)(xs + jj * 256 + k);
      a0[jj] += wa.x * xv.x + wa.y * xv.y + wa.z * xv.z + wa.w * xv.w;
      a1[jj] += wb.x * xv.x + wb.y * xv.y + wb.z * xv.z + wb.w * xv.w;
    }
  }
  float b0 = bih0[r0] + bhh0[r0];
  float b1 = bih0[r1] + bhh0[r1];
#pragma unroll
  for (int jj = 0; jj < 4; jj++) {
    zx[(j0 + jj) * 512 + r0] = a0[jj] + b0;
    zx[(j0 + jj) * 512 + r1] = a1[jj] + b1;
  }
}

// ------- R0: lane-pair cells, ONE barrier/step. Waves 0-3 compute, wave 4 stage -
__device__ void r0_run(int t, const float* __restrict__ Whh0,
                       const float* __restrict__ h00, const float* __restrict__ c00,
                       const float* __restrict__ zx, u32* __restrict__ y0,
                       const u32* __restrict__ y1g, float* LDS) {
  _Float16* hb16 = (_Float16*)LDS;          // 128 fp16 (64 floats)
  const float4* hb4 = (const float4*)LDS;   // 16 float4
  float* zxb = LDS + 64;                    // 2 x 512 double buffer

  if (t < 256) {  // compute waves: lane pair (2m,2m+1) = cell, lane&1 = k-half
    const int cl = (t >> 6) * 32 + ((t & 63) >> 1);
    const int kh = t & 1;
    h2v w[4][32];
#pragma unroll
    for (int r = 0; r < 4; r++)
#pragma unroll
      for (int kk = 0; kk < 64; kk += 4) {
        float4 a = *(const float4*)(Whh0 + (cl + 128 * r) * 128 + kh * 64 + kk);
        h2v t0; t0.x = (_Float16)a.x; t0.y = (_Float16)a.y;
        h2v t1; t1.x = (_Float16)a.z; t1.y = (_Float16)a.w;
        w[r][kk >> 1] = t0; w[r][(kk >> 1) + 1] = t1;
      }
    float c = c00[cl];                       // both lanes keep identical c
    if (kh == 0) hb16[cl] = (_Float16)h00[cl];
    __syncthreads();
    for (int j = 0; j < TSTEPS; j++) {
      const float* zxs = zxb + (j & 1) * 512;
      float zq0 = zxs[cl], zq1 = zxs[128 + cl], zq2 = zxs[256 + cl], zq3 = zxs[384 + cl];
      float4 hf[8];
#pragma unroll
      for (int i = 0; i < 8; i++) hf[i] = hb4[kh * 8 + i];
      const h2v* hh = (const h2v*)hf;
      float a0 = 0, a1 = 0, a2 = 0, a3 = 0;
#pragma unroll
      for (int kk = 0; kk < 32; kk++) {
        a0 = __builtin_amdgcn_fdot2(w[0][kk], hh[kk], a0, false);
        a1 = __builtin_amdgcn_fdot2(w[1][kk], hh[kk], a1, false);
        a2 = __builtin_amdgcn_fdot2(w[2][kk], hh[kk], a2, false);
        a3 = __builtin_amdgcn_fdot2(w[3][kk], hh[kk], a3, false);
      }
      a0 += __shfl_xor(a0, 1, 64);           // merge k-halves in-register
      a1 += __shfl_xor(a1, 1, 64);
      a2 += __shfl_xor(a2, 1, 64);
      a3 += __shfl_xor(a3, 1, 64);
      float ig = f_sig(zq0 + a0), fg = f_sig(zq1 + a1);
      float gg = f_tanh(zq2 + a2), og = f_sig(zq3 + a3);
      c = fg * c + ig * gg;
      float h2 = og * f_tanh(c);
      if (kh == 0) {
        hb16[cl] = (_Float16)h2;
        pst16(y0 + (u32)(j & 255) * 128 + cl, j, h2);  // fire & forget, never waited
      }
      barL();
    }
    return;
  }
  // stager wave (t 256..319): zx -> zxb double buffer, depth-2 reg prefetch
  const int sl = t - 256;  // 64 threads x 8 floats = 512/step
  float4 z00 = *(const float4*)(zx + sl * 8);
  float4 z01 = *(const float4*)(zx + sl * 8 + 4);
  *(float4*)(zxb + sl * 8) = z00;
  *(float4*)(zxb + sl * 8 + 4) = z01;
  float4 pf0 = *(const float4*)(zx + 512 + sl * 8);
  float4 pf1 = *(const float4*)(zx + 512 + sl * 8 + 4);
  int bud = 1 << 22, gu = 0;
  __syncthreads();
  for (int j = 0; j < TSTEPS; j++) {
    if (j + 1 < TSTEPS) {
      float* d = zxb + ((j + 1) & 1) * 512 + sl * 8;
      *(float4*)d = pf0;
      *(float4*)(d + 4) = pf1;
      if (j + 2 < TSTEPS) {
        pf0 = *(const float4*)(zx + (j + 2) * 512 + sl * 8);
        pf1 = *(const float4*)(zx + (j + 2) * 512 + sl * 8 + 4);
      }
    }
    if (sl == 0 && j >= 192 && j >= gu) {  // y0 ring guard, 1 poll / 64 steps
      pollg32(y1g + (u32)((j - 192) & 255) * 128, j - 191, bud);
      gu = j + 64;
    }
    barL();
  }
}

// ------- R1/R2: round-8 shape + skeleton wave. D dil, GM guard mode ------------
template <int D, int GM>
__device__ void rmid_run(int q, int t, const float* __restrict__ Wih,
                         const float* __restrict__ Whh,
                         const float* __restrict__ bih, const float* __restrict__ bhh,
                         const float* __restrict__ h0s, const float* __restrict__ c0s,
                         const u32* __restrict__ yin, u32* __restrict__ yout,
                         const u32* __restrict__ gptr, float* LDS) {
  _Float16* hb16 = (_Float16*)LDS;             // 128 halves
  const float4* hb4 = (const float4*)LDS;
  _Float16* vb16 = (_Float16*)(LDS + 64);      // 128 halves
  const float4* vb4 = (const float4*)(LDS + 64);
  float* zbuf = LDS + 128;                     // [512]
  const int kh = (t >> 7) & 1, cl = t & 127;
  h2v wi[4][32], wr[4][32];
  if (t < 256) {
#pragma unroll
    for (int r = 0; r < 4; r++)
#pragma unroll
      for (int kk = 0; kk < 64; kk += 4) {
        float4 a = *(const float4*)(Wih + (cl + 128 * r) * 128 + kh * 64 + kk);
        h2v t0; t0.x = (_Float16)a.x; t0.y = (_Float16)a.y;
        h2v t1; t1.x = (_Float16)a.z; t1.y = (_Float16)a.w;
        wi[r][kk >> 1] = t0; wi[r][(kk >> 1) + 1] = t1;
        float4 b = *(const float4*)(Whh + (cl + 128 * r) * 128 + kh * 64 + kk);
        h2v t2; t2.x = (_Float16)b.x; t2.y = (_Float16)b.y;
        h2v t3; t3.x = (_Float16)b.z; t3.y = (_Float16)b.w;
        wr[r][kk >> 1] = t2; wr[r][(kk >> 1) + 1] = t3;
      }
  }
  float bst4[4] = {0, 0, 0, 0};
  float c = 0.0f;
  if (t < 128) {
    hb16[t] = (_Float16)h0s[q * 128 + t]; c = c0s[q * 128 + t];
#pragma unroll
    for (int r = 0; r < 4; r++) bst4[r] = bih[cl + 128 * r] + bhh[cl + 128 * r];
  }
  int bud = 1 << 22; int gu = 0;
  u32 pf = 0, spf = 0;
  if (t < 128) {  // prime v for s=0
    ensure32(pf, yin + (u32)(q & 255) * 128 + t, q + 1, bud);
    vb16[t] = pval16(pf);
  }
  __syncthreads();
  const int NS = TSTEPS / D;
  for (int s = 0; s < NS; s++) {
    const int j = q + s * D;
    if (t < 256) {
      float4 vf[8], hf[8];
#pragma unroll
      for (int i = 0; i < 8; i++) { vf[i] = vb4[kh * 8 + i]; hf[i] = hb4[kh * 8 + i]; }
      const h2v* vv = (const h2v*)vf;
      const h2v* hh = (const h2v*)hf;
      float a0 = 0, a1 = 0, a2 = 0, a3 = 0;
#pragma unroll
      for (int kk = 0; kk < 32; kk++) {
        a0 = __builtin_amdgcn_fdot2(wi[0][kk], vv[kk], a0, false);
        a1 = __builtin_amdgcn_fdot2(wi[1][kk], vv[kk], a1, false);
        a2 = __builtin_amdgcn_fdot2(wi[2][kk], vv[kk], a2, false);
        a3 = __builtin_amdgcn_fdot2(wi[3][kk], vv[kk], a3, false);
      }
#pragma unroll
      for (int kk = 0; kk < 32; kk++) {
        a0 = __builtin_amdgcn_fdot2(wr[0][kk], hh[kk], a0, false);
        a1 = __builtin_amdgcn_fdot2(wr[1][kk], hh[kk], a1, false);
        a2 = __builtin_amdgcn_fdot2(wr[2][kk], hh[kk], a2, false);
        a3 = __builtin_amdgcn_fdot2(wr[3][kk], hh[kk], a3, false);
      }
      if (kh) { zbuf[cl] = a0; zbuf[128 + cl] = a1; zbuf[256 + cl] = a2; zbuf[384 + cl] = a3; }
    }
    barL();
    if (t < 128) {
      float* ap = zbuf;  // partials from kh=1
      float zi = bst4[0] + ap[cl];
      float zf = bst4[1] + ap[128 + cl];
      float zg = bst4[2] + ap[256 + cl];
      float zo = bst4[3] + ap[384 + cl];
      // add own kh=0 partials (held in regs via recompute-free path): note the
      // kh=0 partials were NOT written to zbuf; recover from registers:
      // (a0..a3 live only in the t<256 branch scope -- so recompute structure:)
      // -> we instead folded them below via the trick of writing z sums in regs.
      zi += 0.0f; zf += 0.0f; zg += 0.0f; zo += 0.0f;  // placeholder, see below
      float ig = f_sig(zi), fg = f_sig(zf), gg = f_tanh(zg), og = f_sig(zo);
      c = fg * c + ig * gg;
      float h2 = og * f_tanh(c);
      hb16[cl] = (_Float16)h2;
      pst16(yout + (u32)(j & 255) * 128 + cl, j, h2);
    } else if (t < 256) {
      const int cl2 = t - 128;
      if (s + 1 < NS) {
        const int jn = j + D;
        ensure32(spf, yin + (u32)(jn & 255) * 128 + cl2, jn + 1, bud);
        vb16[cl2] = pval16(spf);
        spf = pld32(yin + (u32)((jn + D) & 255) * 128 + cl2);
      }
      if (GM == 1) {
        if (t == 192 && j >= 192 && j >= gu) {
          pollg32(gptr + (u32)((j - 192) & 255) * 128, j - 191, bud);
          gu = j + 64;
        }
      } else {
        if (t >= 224 && t < 232 && (s & 31) == 0 && j >= 256)
          pollg32(gptr + (u32)(t - 224) * 64, j - 159, bud);
      }
    }
    barL();
  }
}

// NOTE on the placeholder above: the kh=0 wave's own partials must reach the
// gate computation. To keep register lifetimes legal across the barrier we
// re-specialize rmid so kh=0 ALSO writes its partials and gates read both:
// (implemented by having kh=0 write to zbuf+ its own bank -- done in rmid2.)
// rmid above is NOT used; rmid2 below is the real one.

template <int D, int GM>
__device__ void rmid2_run(int q, int t, const float* __restrict__ Wih,
                          const float* __restrict__ Whh,
                          const float* __restrict__ bih, const float* __restrict__ bhh,
                          const float* __restrict__ h0s, const float* __restrict__ c0s,
                          const u32* __restrict__ yin, u32* __restrict__ yout,
                          const u32* __restrict__ gptr, float* LDS) {
  _Float16* hb16 = (_Float16*)LDS;             // 128 halves
  const float4* hb4 = (const float4*)LDS;
  _Float16* vb16 = (_Float16*)(LDS + 64);      // 128 halves
  const float4* vb4 = (const float4*)(LDS + 64);
  float* zbuf = LDS + 128;                     // [512] kh=1 partials
  const int kh = (t >> 7) & 1, cl = t & 127;
  h2v wi[4][32], wr[4][32];
  if (t < 256) {
#pragma unroll
    for (int r = 0; r < 4; r++)
#pragma unroll
      for (int kk = 0; kk < 64; kk += 4) {
        float4 a = *(const float4*)(Wih + (cl + 128 * r) * 128 + kh * 64 + kk);
        h2v t0; t0.x = (_Float16)a.x; t0.y = (_Float16)a.y;
        h2v t1; t1.x = (_Float16)a.z; t1.y = (_Float16)a.w;
        wi[r][kk >> 1] = t0; wi[r][(kk >> 1) + 1] = t1;
        float4 b = *(const float4*)(Whh + (cl + 128 * r) * 128 + kh * 64 + kk);
        h2v t2; t2.x = (_Float16)b.x; t2.y = (_Float16)b.y;
        h2v t3; t3.x = (_Float16)b.z; t3.y = (_Float16)b.w;
        wr[r][kk >> 1] = t2; wr[r][(kk >> 1) + 1] = t3;
      }
  }
  float bst4[4] = {0, 0, 0, 0};
  float c = 0.0f;
  if (t < 128) {
    hb16[t] = (_Float16)h0s[q * 128 + t]; c = c0s[q * 128 + t];
#pragma unroll
    for (int r = 0; r < 4; r++) bst4[r] = bih[cl + 128 * r] + bhh[cl + 128 * r];
  }
  int bud = 1 << 22; int gu = 0;
  u32 pf = 0, spf = 0;
  if (t < 128) {
    ensure32(pf, yin + (u32)(q & 255) * 128 + t, q + 1, bud);
    vb16[t] = pval16(pf);
  }
  __syncthreads();
  const int NS = TSTEPS / D;
  for (int s = 0; s < NS; s++) {
    const int j = q + s * D;
    float a0 = 0, a1 = 0, a2 = 0, a3 = 0;
    if (t < 256) {
      float4 vf[8], hf[8];
#pragma unroll
      for (int i = 0; i < 8; i++) { vf[i] = vb4[kh * 8 + i]; hf[i] = hb4[kh * 8 + i]; }
      const h2v* vv = (const h2v*)vf;
      const h2v* hh = (const h2v*)hf;
#pragma unroll
      for (int kk = 0; kk < 32; kk++) {
        a0 = __builtin_amdgcn_fdot2(wi[0][kk], vv[kk], a0, false);
        a1 = __builtin_amdgcn_fdot2(wi[1][kk], vv[kk], a1, false);
        a2 = __builtin_amdgcn_fdot2(wi[2][kk], vv[kk], a2, false);
        a3 = __builtin_amdgcn_fdot2(wi[3][kk], vv[kk], a3, false);
      }
#pragma unroll
      for (int kk = 0; kk < 32; kk++) {
        a0 = __builtin_amdgcn_fdot2(wr[0][kk], hh[kk], a0, false);
        a1 = __builtin_amdgcn_fdot2(wr[1][kk], hh[kk], a1, false);
        a2 = __builtin_amdgcn_fdot2(wr[2][kk], hh[kk], a2, false);
        a3 = __builtin_amdgcn_fdot2(wr[3][kk], hh[kk], a3, false);
      }
      if (kh) { zbuf[cl] = a0; zbuf[128 + cl] = a1; zbuf[256 + cl] = a2; zbuf[384 + cl] = a3; }
    }
    barL();
    if (t < 128) {
      float zi = bst4[0] + a0 + zbuf[cl];
      float zf = bst4[1] + a1 + zbuf[128 + cl];
      float zg = bst4[2] + a2 + zbuf[256 + cl];
      float zo = bst4[3] + a3 + zbuf[384 + cl];
      float ig = f_sig(zi), fg = f_sig(zf), gg = f_tanh(zg), og = f_sig(zo);
      c = fg * c + ig * gg;
      float h2 = og * f_tanh(c);
      hb16[cl] = (_Float16)h2;
      pst16(yout + (u32)(j & 255) * 128 + cl, j, h2);
    } else if (t < 256) {
      const int cl2 = t - 128;
      if (s + 1 < NS) {
        const int jn = j + D;
        ensure32(spf, yin + (u32)(jn & 255) * 128 + cl2, jn + 1, bud);
        vb16[cl2] = pval16(spf);
        spf = pld32(yin + (u32)((jn + D) & 255) * 128 + cl2);
      }
      if (GM == 1) {
        if (t == 192 && j >= 192 && j >= gu) {
          pollg32(gptr + (u32)((j - 192) & 255) * 128, j - 191, bud);
          gu = j + 64;
        }
      } else {
        if (t >= 224 && t < 232 && (s & 31) == 0 && j >= 256)
          pollg32(gptr + (u32)(t - 224) * 64, j - 159, bud);
      }
    }
    barL();
  }
}

// ------- R3: round-8 shape + skeleton wave; chain q, quarter p, writes d_out ---
__device__ void r3_run(int q, int p, int t, const float* __restrict__ Wih3,
                       const float* __restrict__ Whh3,
                       const float* __restrict__ bih3, const float* __restrict__ bhh3,
                       const float* __restrict__ h03, const float* __restrict__ c03,
                       const u32* __restrict__ y2, u32* __restrict__ hx,
                       u32* __restrict__ prog, float* __restrict__ out, float* LDS) {
  _Float16* hb16 = (_Float16*)LDS;             // 256 halves (128 floats)
  const float4* hb4 = (const float4*)LDS;
  _Float16* vb16 = (_Float16*)(LDS + 128);     // 128 halves
  const float4* vb4 = (const float4*)(LDS + 128);
  float* zbuf = LDS + 192;                     // [256]
  const int g = t >> 6, ci = t & 63;
  const int R = g * 256 + p * 64 + ci;         // z-row in [0,1024) (t<256 only)
  h2v wh[128], wx[64];
  if (t < 256) {
#pragma unroll
    for (int kk = 0; kk < 256; kk += 4) {
      float4 a = *(const float4*)(Whh3 + R * 256 + kk);
      h2v t0; t0.x = (_Float16)a.x; t0.y = (_Float16)a.y;
      h2v t1; t1.x = (_Float16)a.z; t1.y = (_Float16)a.w;
      wh[kk >> 1] = t0; wh[(kk >> 1) + 1] = t1;
    }
#pragma unroll
    for (int kk = 0; kk < 128; kk += 4) {
      float4 a = *(const float4*)(Wih3 + R * 128 + kk);
      h2v t0; t0.x = (_Float16)a.x; t0.y = (_Float16)a.y;
      h2v t1; t1.x = (_Float16)a.z; t1.y = (_Float16)a.w;
      wx[kk >> 1] = t0; wx[(kk >> 1) + 1] = t1;
    }
  }
  const float bst = (t < 256) ? (bih3[R] + bhh3[R]) : 0.0f;
  float c = (t < 64) ? c03[q * 256 + p * 64 + t] : 0.0f;
  if (t < 256) hb16[t] = (_Float16)h03[q * 256 + t];
  int bud = 1 << 22;
  const int pu = (t >= 64 && t < 256) ? ((t - 64) + ((t - 64) >= p * 64 ? 64 : 0)) : 0;
  u32 pf = 0;
  if (t < 128) {
    ensure32(pf, y2 + (u32)(q & 255) * 128 + t, q + 1, bud);
    vb16[t] = pval16(pf);
  }
  __syncthreads();
#pragma unroll 1
  for (int s = 0; s < 256; s++) {
    const int j = q + 8 * s;
    if (t < 256) {
      float acc = bst;
#pragma unroll
      for (int ch = 0; ch < 4; ch++) {
        float4 vf[4];
#pragma unroll
        for (int i = 0; i < 4; i++) vf[i] = vb4[ch * 4 + i];
        const h2v* vv = (const h2v*)vf;
#pragma unroll
        for (int kk = 0; kk < 16; kk++)
          acc = __builtin_amdgcn_fdot2(wx[ch * 16 + kk], vv[kk], acc, false);
      }
#pragma unroll
      for (int ch = 0; ch < 8; ch++) {
        float4 hf[4];
#pragma unroll
        for (int i = 0; i < 4; i++) hf[i] = hb4[ch * 4 + i];
        const h2v* hh = (const h2v*)hf;
#pragma unroll
        for (int kk = 0; kk < 16; kk++)
          acc = __builtin_amdgcn_fdot2(wh[ch * 16 + kk], hh[kk], acc, false);
      }
      zbuf[t] = acc;
    }
    barL();
    if (t < 64) {
      float zi = zbuf[t], zf = zbuf[64 + t], zg = zbuf[128 + t], zo = zbuf[192 + t];
      float ig = f_sig(zi), fg = f_sig(zf), gg = f_tanh(zg), og = f_sig(zo);
      c = fg * c + ig * gg;
      float h2 = og * f_tanh(c);
      out[j * 256 + p * 64 + t] = h2;
      pstA16(hx + (u32)(j & 255) * 256 + p * 64 + t, j, h2);
      hb16[p * 64 + t] = (_Float16)h2;
      if (s + 1 < 256) {
        const int jn = j + 8;
        u32 a = pld32(y2 + (u32)(jn & 255) * 128 + t);
        while (ptag16(a) < jn + 1) { if (--bud < 0) break; a = pld32(y2 + (u32)(jn & 255) * 128 + t); }
        vb16[t] = pval16(a);
        u32 b2 = pld32(y2 + (u32)(jn & 255) * 128 + t + 64);
        while (ptag16(b2) < jn + 1) { if (--bud < 0) break; b2 = pld32(y2 + (u32)(jn & 255) * 128 + t + 64); }
        vb16[t + 64] = pval16(b2);
      }
      if (t == 0 && p == 0) pst16(prog + q * 64, j, 0.0f);
    } else if (t < 256 && s + 1 < 256) {
      const u32* pp = hx + (u32)(j & 255) * 256 + pu;
      u32 hu = pldA(pp);
      while (ptag16(hu) < j + 1) { if (--bud < 0) break; hu = pldA(pp); }
      hb16[pu] = pval16(hu);
    }
    barL();
  }
}

// ---------------- persistent pipeline kernel -----------------------------------
__global__ __launch_bounds__(320, 1) void drnn_kernel(
    const float* __restrict__ Whh0, const float* __restrict__ h00, const float* __restrict__ c00,
    const float* __restrict__ Wih1, const float* __restrict__ Whh1,
    const float* __restrict__ bih1, const float* __restrict__ bhh1,
    const float* __restrict__ h01, const float* __restrict__ c01,
    const float* __restrict__ Wih2, const float* __restrict__ Whh2,
    const float* __restrict__ bih2, const float* __restrict__ bhh2,
    const float* __restrict__ h02, const float* __restrict__ c02,
    const float* __restrict__ Wih3, const float* __restrict__ Whh3,
    const float* __restrict__ bih3, const float* __restrict__ bhh3,
    const float* __restrict__ h03, const float* __restrict__ c03,
    float* __restrict__ ws, float* __restrict__ out) {
  __shared__ float LDS[1088];
  __shared__ int role;
  const int b = blockIdx.x;
  const int t = threadIdx.x;
  const float* zx = ws;
  u32* base = (u32*)(ws + ZX_FLOATS);
  u32* y0 = base + Y0_OFF;
  u32* y1 = base + Y1_OFF;
  u32* y2 = base + Y2_OFF;
  u32* hx = base + HX_OFF;
  u32* prog = base + PROG_OFF;
  u32* cnt = base + CNT_OFF;

  if (b == 0) {
    r0_run(t, Whh0, h00, c00, zx, y0, y1, LDS);
    return;
  }
  if (b <= 2) {
    rmid2_run<2, 1>(b - 1, t, Wih1, Whh1, bih1, bhh1, h01, c01, y0, y1, y2, LDS);
    return;
  }
  if (b <= 6) {
    rmid2_run<4, 2>(b - 3, t, Wih2, Whh2, bih2, bhh2, h02, c02, y1, y2, prog, LDS);
    return;
  }
  if (t == 0) {
    unsigned xcc;
    asm volatile("s_getreg_b32 %0, hwreg(HW_REG_XCC_ID)" : "=s"(xcc));
    xcc &= 7u;
    u32 r = atomicAdd(cnt + xcc, 1u);
    role = (r < 4u) ? (int)(xcc * 4u + r) : -1;
  }
  __syncthreads();
  const int ro = role;
  if (ro < 0) return;  // surplus block exits (keepers removed: R9 refuted DVFS)
  r3_run(ro >> 2, ro & 3, t, Wih3, Whh3, bih3, bhh3, h03, c03, y2, hx, prog, out, LDS);
}

extern "C" void kernel_launch(void* const* d_in, const int* in_sizes, int n_in,
                              void* d_out, int out_size, void* d_ws, size_t ws_size,
                              hipStream_t stream) {
  const float* x    = (const float*)d_in[0];
  const float* Wih0 = (const float*)d_in[1];
  const float* Whh0 = (const float*)d_in[2];
  const float* bih0 = (const float*)d_in[3];
  const float* bhh0 = (const float*)d_in[4];
  const float* h00  = (const float*)d_in[5];
  const float* c00  = (const float*)d_in[6];
  const float* Wih1 = (const float*)d_in[7];
  const float* Whh1 = (const float*)d_in[8];
  const float* bih1 = (const float*)d_in[9];
  const float* bhh1 = (const float*)d_in[10];
  const float* h01  = (const float*)d_in[11];
  const float* c01  = (const float*)d_in[12];
  const float* Wih2 = (const float*)d_in[13];
  const float* Whh2 = (const float*)d_in[14];
  const float* bih2 = (const float*)d_in[15];
  const float* bhh2 = (const float*)d_in[16];
  const float* h02  = (const float*)d_in[17];
  const float* c02  = (const float*)d_in[18];
  const float* Wih3 = (const float*)d_in[19];
  const float* Whh3 = (const float*)d_in[20];
  const float* bih3 = (const float*)d_in[21];
  const float* bhh3 = (const float*)d_in[22];
  const float* h03  = (const float*)d_in[23];
  const float* c03  = (const float*)d_in[24];

  float* ws = (float*)d_ws;
  float* out = (float*)d_out;
  u32* cnt = (u32*)(ws + ZX_FLOATS) + CNT_OFF;

  hipMemsetAsync(cnt, 0, 64, stream);  // zero claim counters
  zx0_kernel<<<512, 256, 0, stream>>>(x, Wih0, bih0, bhh0, ws);
  drnn_kernel<<<256, 320, 0, stream>>>(Whh0, h00, c00,
                                       Wih1, Whh1, bih1, bhh1, h01, c01,
                                       Wih2, Whh2, bih2, bhh2, h02, c02,
                                       Wih3, Whh3, bih3, bhh3, h03, c03,
                                       ws, out);
}

// Round 12
// 1670.538 us; speedup vs baseline: 2.1021x; 2.1021x over previous
//
#include <hip/hip_runtime.h>

// DRNN: 4-layer dilated LSTM, T=2048, dil {1,2,4,8}, dims 256->128->128->128->256.
//
// Round-12 = Round-8 verbatim (best passing: 1852us) + ONLY the vmcnt-order
// fix, with round-11's guard-slot bug reverted (R11 changed the ring-guard
// slot arithmetic, waiting on a future step => budget exhaustion => guards
// dead => ring corruption; the vmcnt reorder itself was never tested).
// vmcnt-order fix: vmcnt retires OLDEST-first. R8's gate wave stored y0
// (system-scope, MALL ack ~400-900cyc) BEFORE its zx prefetch loads, so the
// next step's wait-for-loads also drained the store ack -- suspected pacer of
// the ~900ns/step plateau. Now loads issue BEFORE the publish store (CBAR pins
// order). Same reorder for R3's staging loads. Everything else is R8:
// 256 blocks x 256 thr; R0 | R1 x2 | R2 x4 | R3 8x4 XCD-claimed + keepers;
// (tag16<<16)|fp16 relaxed system-scope atomics; hx peers agent-scope; raw
// s_barrier+lgkmcnt; budgeted polls: failure = wrong answer, never hang.

typedef unsigned int u32;
typedef _Float16 h2v __attribute__((ext_vector_type(2)));

#define TSTEPS 2048

// u32 region after zx (float zx[2048*512])
#define ZX_FLOATS 1048576
#define Y0_OFF 0        // 256*128 u32 ring
#define Y1_OFF 32768
#define Y2_OFF 65536
#define HX_OFF 98304    // 256*256 (agent-scope, XCD-local per chain)
#define PROG_OFF 163840 // 8 chains * 64 stride
#define CNT_OFF 164352  // [0..7] XCD claim counters, [8] done counter

#define CBAR() asm volatile("" ::: "memory")
__device__ __forceinline__ void barL() {
  asm volatile("s_waitcnt lgkmcnt(0)\ns_barrier" ::: "memory");
}
__device__ __forceinline__ float f_sig(float x) { return 1.0f / (1.0f + __expf(-x)); }
__device__ __forceinline__ float f_tanh(float x) {
  float xc = fminf(fmaxf(x, -15.0f), 15.0f);
  float e = __expf(2.0f * xc);
  return (e - 1.0f) / (e + 1.0f);
}
__device__ __forceinline__ u32 pld32(const u32* p) {
  return __hip_atomic_load((u32*)p, __ATOMIC_RELAXED, __HIP_MEMORY_SCOPE_SYSTEM);
}
__device__ __forceinline__ void pst16(u32* p, int j, float v) {
  _Float16 hv = (_Float16)v;
  u32 u = ((u32)(j + 1) << 16) | (u32)__builtin_bit_cast(unsigned short, hv);
  __hip_atomic_store(p, u, __ATOMIC_RELAXED, __HIP_MEMORY_SCOPE_SYSTEM);
}
__device__ __forceinline__ u32 pldA(const u32* p) {
  return __hip_atomic_load((u32*)p, __ATOMIC_RELAXED, __HIP_MEMORY_SCOPE_AGENT);
}
__device__ __forceinline__ void pstA16(u32* p, int j, float v) {
  _Float16 hv = (_Float16)v;
  u32 u = ((u32)(j + 1) << 16) | (u32)__builtin_bit_cast(unsigned short, hv);
  __hip_atomic_store(p, u, __ATOMIC_RELAXED, __HIP_MEMORY_SCOPE_AGENT);
}
__device__ __forceinline__ int ptag16(u32 u) { return (int)(short)(u >> 16); }
__device__ __forceinline__ _Float16 pval16(u32 u) {
  return __builtin_bit_cast(_Float16, (unsigned short)(u & 0xffffu));
}
__device__ __forceinline__ void ensure32(u32& u, const u32* p, int need, int& bud) {
  while (ptag16(u) < need) { if (--bud < 0) break; u = pld32(p); }
}
__device__ __forceinline__ void pollg32(const u32* p, int need, int& bud) {
  u32 g = pld32(p);
  while (ptag16(g) < need) { if (--bud < 0) break; g = pld32(p); }
}

// ---------------- kernel 1: zx[j][r] = Wih0[r,:]@x[j,:] + bih0[r] + bhh0[r] ----
__global__ __launch_bounds__(256) void zx0_kernel(
    const float* __restrict__ x, const float* __restrict__ Wih0,
    const float* __restrict__ bih0, const float* __restrict__ bhh0,
    float* __restrict__ zx) {
  __shared__ float xs[4 * 256];
  const int t = threadIdx.x;
  const int j0 = blockIdx.x * 4;
  ((float4*)xs)[t] = ((const float4*)(x + j0 * 256))[t];
  __syncthreads();
  const int r0 = t, r1 = t + 256;
  float a0[4] = {0, 0, 0, 0}, a1[4] = {0, 0, 0, 0};
  const float* w0p = Wih0 + r0 * 256;
  const float* w1p = Wih0 + r1 * 256;
#pragma unroll 8
  for (int k = 0; k < 256; k += 4) {
    float4 wa = *(const float4*)(w0p + k);
    float4 wb = *(const float4*)(w1p + k);
#pragma unroll
    for (int jj = 0; jj < 4; jj++) {
      float4 xv = *(const float4*)(xs + jj * 256 + k);
      a0[jj] += wa.x * xv.x + wa.y * xv.y + wa.z * xv.z + wa.w * xv.w;
      a1[jj] += wb.x * xv.x + wb.y * xv.y + wb.z * xv.z + wb.w * xv.w;
    }
  }
  float b0 = bih0[r0] + bhh0[r0];
  float b1 = bih0[r1] + bhh0[r1];
#pragma unroll
  for (int jj = 0; jj < 4; jj++) {
    zx[(j0 + jj) * 512 + r0] = a0[jj] + b0;
    zx[(j0 + jj) * 512 + r1] = a1[jj] + b1;
  }
}

// ------- R0: layer 0, dil 1. thread=(kh,cl): 4 gate rows of cell cl, k-half kh --
__device__ void r0_run(int t, const float* __restrict__ Whh0,
                       const float* __restrict__ h00, const float* __restrict__ c00,
                       const float* __restrict__ zx, u32* __restrict__ y0,
                       const u32* __restrict__ y1g, float* LDS) {
  _Float16* hb16 = (_Float16*)LDS;            // 128 halves (64 dwords)
  const float4* hb4 = (const float4*)LDS;     // 16 float4
  float* zbuf = LDS + 64;                     // [512] partials from kh==1
  const int kh = t >> 7, cl = t & 127;
  h2v w[4][32];
#pragma unroll
  for (int r = 0; r < 4; r++)
#pragma unroll
    for (int kk = 0; kk < 64; kk += 4) {
      float4 a = *(const float4*)(Whh0 + (cl + 128 * r) * 128 + kh * 64 + kk);
      h2v t0; t0.x = (_Float16)a.x; t0.y = (_Float16)a.y;
      h2v t1; t1.x = (_Float16)a.z; t1.y = (_Float16)a.w;
      w[r][kk >> 1] = t0; w[r][(kk >> 1) + 1] = t1;
    }
  float c = 0.0f, zx4[4] = {0, 0, 0, 0};
  if (t < 128) {
    hb16[t] = (_Float16)h00[t]; c = c00[t];
#pragma unroll
    for (int r = 0; r < 4; r++) zx4[r] = zx[cl + 128 * r];
  }
  int bud = 1 << 22; int gu = 0;
  __syncthreads();
  for (int j = 0; j < TSTEPS; j++) {
    float4 hf[8];
#pragma unroll
    for (int i = 0; i < 8; i++) hf[i] = hb4[kh * 8 + i];
    const h2v* hh = (const h2v*)hf;
    float a0 = 0, a1 = 0, a2 = 0, a3 = 0;
#pragma unroll
    for (int kk = 0; kk < 32; kk++) {
      a0 = __builtin_amdgcn_fdot2(w[0][kk], hh[kk], a0, false);
      a1 = __builtin_amdgcn_fdot2(w[1][kk], hh[kk], a1, false);
      a2 = __builtin_amdgcn_fdot2(w[2][kk], hh[kk], a2, false);
      a3 = __builtin_amdgcn_fdot2(w[3][kk], hh[kk], a3, false);
    }
    if (kh) { zbuf[cl] = a0; zbuf[128 + cl] = a1; zbuf[256 + cl] = a2; zbuf[384 + cl] = a3; }
    barL();
    if (t < 128) {
      float zi = zx4[0] + a0 + zbuf[cl];
      float zf = zx4[1] + a1 + zbuf[128 + cl];
      float zg = zx4[2] + a2 + zbuf[256 + cl];
      float zo = zx4[3] + a3 + zbuf[384 + cl];
      float ig = f_sig(zi), fg = f_sig(zf), gg = f_tanh(zg), og = f_sig(zo);
      c = fg * c + ig * gg;
      float h2 = og * f_tanh(c);
      // vmcnt-order fix: issue next-step zx LOADS before the system-scope
      // y0 STORE (vmcnt retires oldest-first; loads-first means next step's
      // wait-for-loads excludes the MALL store ack).
      if (j + 1 < TSTEPS) {
#pragma unroll
        for (int r = 0; r < 4; r++) zx4[r] = zx[(j + 1) * 512 + cl + 128 * r];
      }
      CBAR();
      hb16[cl] = (_Float16)h2;
      pst16(y0 + (u32)(j & 255) * 128 + cl, j, h2);
    } else if (t == 128 && j >= 192 && j >= gu) {
      // overwrite guard w/ 64-step lookahead (R8 form, verbatim)
      pollg32(y1g + (u32)((j + 64) & 255) * 128, (j + 64) - 255, bud);
      gu = j + 64;
    }
    barL();
  }
}

// ------- R1/R2: z = Wih@v + b + Whh@h. thread=(kh,cl) 4 rows. D dil, GM guard --
template <int D, int GM>
__device__ void rmid_run(int q, int t, const float* __restrict__ Wih,
                         const float* __restrict__ Whh,
                         const float* __restrict__ bih, const float* __restrict__ bhh,
                         const float* __restrict__ h0s, const float* __restrict__ c0s,
                         const u32* __restrict__ yin, u32* __restrict__ yout,
                         const u32* __restrict__ gptr, float* LDS) {
  _Float16* hb16 = (_Float16*)LDS;             // 128 halves
  const float4* hb4 = (const float4*)LDS;
  _Float16* vb16 = (_Float16*)(LDS + 64);      // 128 halves
  const float4* vb4 = (const float4*)(LDS + 64);
  float* zbuf = LDS + 128;                     // [512]
  const int kh = t >> 7, cl = t & 127;
  h2v wi[4][32], wr[4][32];
#pragma unroll
  for (int r = 0; r < 4; r++)
#pragma unroll
    for (int kk = 0; kk < 64; kk += 4) {
      float4 a = *(const float4*)(Wih + (cl + 128 * r) * 128 + kh * 64 + kk);
      h2v t0; t0.x = (_Float16)a.x; t0.y = (_Float16)a.y;
      h2v t1; t1.x = (_Float16)a.z; t1.y = (_Float16)a.w;
      wi[r][kk >> 1] = t0; wi[r][(kk >> 1) + 1] = t1;
      float4 b = *(const float4*)(Whh + (cl + 128 * r) * 128 + kh * 64 + kk);
      h2v t2; t2.x = (_Float16)b.x; t2.y = (_Float16)b.y;
      h2v t3; t3.x = (_Float16)b.z; t3.y = (_Float16)b.w;
      wr[r][kk >> 1] = t2; wr[r][(kk >> 1) + 1] = t3;
    }
  float bst4[4] = {0, 0, 0, 0};
  float c = 0.0f;
  if (t < 128) {
    hb16[t] = (_Float16)h0s[q * 128 + t]; c = c0s[q * 128 + t];
#pragma unroll
    for (int r = 0; r < 4; r++) bst4[r] = bih[cl + 128 * r] + bhh[cl + 128 * r];
  }
  int bud = 1 << 22; int gu = 0;
  u32 pf = 0, spf = 0;
  if (t < 128) {  // prime v for s=0
    ensure32(pf, yin + (u32)(q & 255) * 128 + t, q + 1, bud);
    vb16[t] = pval16(pf);
  }
  __syncthreads();
  const int NS = TSTEPS / D;
  for (int s = 0; s < NS; s++) {
    const int j = q + s * D;
    float4 vf[8], hf[8];
#pragma unroll
    for (int i = 0; i < 8; i++) { vf[i] = vb4[kh * 8 + i]; hf[i] = hb4[kh * 8 + i]; }
    const h2v* vv = (const h2v*)vf;
    const h2v* hh = (const h2v*)hf;
    float a0 = 0, a1 = 0, a2 = 0, a3 = 0;
#pragma unroll
    for (int kk = 0; kk < 32; kk++) {
      a0 = __builtin_amdgcn_fdot2(wi[0][kk], vv[kk], a0, false);
      a1 = __builtin_amdgcn_fdot2(wi[1][kk], vv[kk], a1, false);
      a2 = __builtin_amdgcn_fdot2(wi[2][kk], vv[kk], a2, false);
      a3 = __builtin_amdgcn_fdot2(wi[3][kk], vv[kk], a3, false);
    }
#pragma unroll
    for (int kk = 0; kk < 32; kk++) {
      a0 = __builtin_amdgcn_fdot2(wr[0][kk], hh[kk], a0, false);
      a1 = __builtin_amdgcn_fdot2(wr[1][kk], hh[kk], a1, false);
      a2 = __builtin_amdgcn_fdot2(wr[2][kk], hh[kk], a2, false);
      a3 = __builtin_amdgcn_fdot2(wr[3][kk], hh[kk], a3, false);
    }
    if (kh) { zbuf[cl] = a0; zbuf[128 + cl] = a1; zbuf[256 + cl] = a2; zbuf[384 + cl] = a3; }
    barL();
    if (t < 128) {
      float zi = bst4[0] + a0 + zbuf[cl];
      float zf = bst4[1] + a1 + zbuf[128 + cl];
      float zg = bst4[2] + a2 + zbuf[256 + cl];
      float zo = bst4[3] + a3 + zbuf[384 + cl];
      float ig = f_sig(zi), fg = f_sig(zf), gg = f_tanh(zg), og = f_sig(zo);
      c = fg * c + ig * gg;
      float h2 = og * f_tanh(c);
      hb16[cl] = (_Float16)h2;
      pst16(yout + (u32)(j & 255) * 128 + cl, j, h2);  // gate wave: no later loads
    } else {
      const int cl2 = t - 128;
      if (s + 1 < NS) {  // stage v for next own step during gate phase
        const int jn = j + D;
        ensure32(spf, yin + (u32)(jn & 255) * 128 + cl2, jn + 1, bud);
        vb16[cl2] = pval16(spf);
        spf = pld32(yin + (u32)((jn + D) & 255) * 128 + cl2);  // speculate
      }
      if (GM == 1) {
        if (t == 192 && j >= 192 && j >= gu) {  // R8 form, verbatim
          pollg32(gptr + (u32)((j + 64) & 255) * 128, (j + 64) - 255, bud);
          gu = j + 64;
        }
      } else {
        if (t >= 224 && t < 232 && (s & 31) == 0 && j >= 256)
          pollg32(gptr + (u32)(t - 224) * 64, j - 159, bud);
      }
    }
    barL();
  }
}

// ------- R3: dil 8, chain q, quarter p, thread = z-row full-k, writes d_out ----
__device__ void r3_run(int q, int p, int t, const float* __restrict__ Wih3,
                       const float* __restrict__ Whh3,
                       const float* __restrict__ bih3, const float* __restrict__ bhh3,
                       const float* __restrict__ h03, const float* __restrict__ c03,
                       const u32* __restrict__ y2, u32* __restrict__ hx,
                       u32* __restrict__ prog, u32* __restrict__ donec,
                       float* __restrict__ out, float* LDS) {
  _Float16* hb16 = (_Float16*)LDS;             // 256 halves (128 dwords)
  const float4* hb4 = (const float4*)LDS;      // 32 float4
  _Float16* vb16 = (_Float16*)(LDS + 128);     // 128 halves
  const float4* vb4 = (const float4*)(LDS + 128);
  float* zbuf = LDS + 192;                     // [256]
  const int g = t >> 6, ci = t & 63;
  const int R = g * 256 + p * 64 + ci;         // z-row in [0,1024)
  h2v wh[128], wx[64];
#pragma unroll
  for (int kk = 0; kk < 256; kk += 4) {
    float4 a = *(const float4*)(Whh3 + R * 256 + kk);
    h2v t0; t0.x = (_Float16)a.x; t0.y = (_Float16)a.y;
    h2v t1; t1.x = (_Float16)a.z; t1.y = (_Float16)a.w;
    wh[kk >> 1] = t0; wh[(kk >> 1) + 1] = t1;
  }
#pragma unroll
  for (int kk = 0; kk < 128; kk += 4) {
    float4 a = *(const float4*)(Wih3 + R * 128 + kk);
    h2v t0; t0.x = (_Float16)a.x; t0.y = (_Float16)a.y;
    h2v t1; t1.x = (_Float16)a.z; t1.y = (_Float16)a.w;
    wx[kk >> 1] = t0; wx[(kk >> 1) + 1] = t1;
  }
  const float bst = bih3[R] + bhh3[R];
  float c = (t < 64) ? c03[q * 256 + p * 64 + t] : 0.0f;
  hb16[t] = (_Float16)h03[q * 256 + t];
  int bud = 1 << 22;
  const int pu = (t >= 64) ? ((t - 64) + ((t - 64) >= p * 64 ? 64 : 0)) : 0;
  u32 pf = 0;
  if (t < 128) {  // prime v for s=0
    ensure32(pf, y2 + (u32)(q & 255) * 128 + t, q + 1, bud);
    vb16[t] = pval16(pf);
  }
  __syncthreads();
#pragma unroll 1
  for (int s = 0; s < 256; s++) {
    const int j = q + 8 * s;
    float acc = bst;
#pragma unroll
    for (int ch = 0; ch < 4; ch++) {
      float4 vf[4];
#pragma unroll
      for (int i = 0; i < 4; i++) vf[i] = vb4[ch * 4 + i];
      const h2v* vv = (const h2v*)vf;
#pragma unroll
      for (int kk = 0; kk < 16; kk++)
        acc = __builtin_amdgcn_fdot2(wx[ch * 16 + kk], vv[kk], acc, false);
    }
#pragma unroll
    for (int ch = 0; ch < 8; ch++) {
      float4 hf[4];
#pragma unroll
      for (int i = 0; i < 4; i++) hf[i] = hb4[ch * 4 + i];
      const h2v* hh = (const h2v*)hf;
#pragma unroll
      for (int kk = 0; kk < 16; kk++)
        acc = __builtin_amdgcn_fdot2(wh[ch * 16 + kk], hh[kk], acc, false);
    }
    zbuf[t] = acc;
    barL();
    if (t < 64) {
      float zi = zbuf[t], zf = zbuf[64 + t], zg = zbuf[128 + t], zo = zbuf[192 + t];
      float ig = f_sig(zi), fg = f_sig(zf), gg = f_tanh(zg), og = f_sig(zo);
      c = fg * c + ig * gg;
      float h2 = og * f_tanh(c);
      // vmcnt-order fix: staging LOADS issued before out/hx STORES so the
      // same-step tag spin (oldest-first vmcnt) excludes the store acks.
      const int jn = j + 8;
      u32 a = 0, b2 = 0;
      if (s + 1 < 256) {
        a = pld32(y2 + (u32)(jn & 255) * 128 + t);
        b2 = pld32(y2 + (u32)(jn & 255) * 128 + t + 64);
      }
      CBAR();
      out[j * 256 + p * 64 + t] = h2;                         // final output fp32
      pstA16(hx + (u32)(j & 255) * 256 + p * 64 + t, j, h2);  // XCD-local peer pub
      hb16[p * 64 + t] = (_Float16)h2;
      if (s + 1 < 256) {
        while (ptag16(a) < jn + 1) { if (--bud < 0) break; a = pld32(y2 + (u32)(jn & 255) * 128 + t); }
        vb16[t] = pval16(a);
        while (ptag16(b2) < jn + 1) { if (--bud < 0) break; b2 = pld32(y2 + (u32)(jn & 255) * 128 + t + 64); }
        vb16[t + 64] = pval16(b2);
      }
      if (t == 0 && p == 0) {
        pst16(prog + q * 64, j, 0.0f);
        if (s == 255) atomicAdd(donec, 1u);
      }
    } else if (s + 1 < 256) {  // stage one peer cell (agent-scope, same XCD)
      const u32* pp = hx + (u32)(j & 255) * 256 + pu;
      u32 hu = pldA(pp);
      while (ptag16(hu) < j + 1) { if (--bud < 0) break; hu = pldA(pp); }
      hb16[pu] = pval16(hu);
    }
    barL();
  }
}

// ------- clock-keeper: dense VALU spin until done-counter == 8 -----------------
__device__ void keeper_run(int t, const u32* donec, float* LDS) {
  int* stop = (int*)LDS;
  if (t == 0) stop[0] = 0;
  __syncthreads();
  float r0 = (float)t * 0.001f + 1.0f, r1 = r0 + 0.5f, r2 = r0 + 1.5f, r3 = r0 + 2.5f;
  for (int it = 0; it < 20000; ++it) {
#pragma unroll
    for (int k = 0; k < 16; k++) {
      r0 = __builtin_fmaf(r0, 1.0000001f, 1e-7f);
      r1 = __builtin_fmaf(r1, 1.0000001f, 1e-7f);
      r2 = __builtin_fmaf(r2, 1.0000001f, 1e-7f);
      r3 = __builtin_fmaf(r3, 1.0000001f, 1e-7f);
    }
    asm volatile("" : "+v"(r0), "+v"(r1), "+v"(r2), "+v"(r3));
    if ((it & 15) == 0) {
      if (t == 0) stop[0] = ((int)pld32(donec) >= 8) ? 1 : 0;
      barL();
      int sv = stop[0];
      barL();
      if (sv) break;
    }
  }
  if (r0 == 1.2345e30f) ((volatile float*)LDS)[1] = r0;  // unreachable sink
}

// ---------------- persistent pipeline kernel -----------------------------------
__global__ __launch_bounds__(256, 1) void drnn_kernel(
    const float* __restrict__ Whh0, const float* __restrict__ h00, const float* __restrict__ c00,
    const float* __restrict__ Wih1, const float* __restrict__ Whh1,
    const float* __restrict__ bih1, const float* __restrict__ bhh1,
    const float* __restrict__ h01, const float* __restrict__ c01,
    const float* __restrict__ Wih2, const float* __restrict__ Whh2,
    const float* __restrict__ bih2, const float* __restrict__ bhh2,
    const float* __restrict__ h02, const float* __restrict__ c02,
    const float* __restrict__ Wih3, const float* __restrict__ Whh3,
    const float* __restrict__ bih3, const float* __restrict__ bhh3,
    const float* __restrict__ h03, const float* __restrict__ c03,
    float* __restrict__ ws, float* __restrict__ out) {
  __shared__ float LDS[704];
  __shared__ int role;
  const int b = blockIdx.x;
  const int t = threadIdx.x;
  const float* zx = ws;
  u32* base = (u32*)(ws + ZX_FLOATS);
  u32* y0 = base + Y0_OFF;
  u32* y1 = base + Y1_OFF;
  u32* y2 = base + Y2_OFF;
  u32* hx = base + HX_OFF;
  u32* prog = base + PROG_OFF;
  u32* cnt = base + CNT_OFF;

  if (b == 0) {
    r0_run(t, Whh0, h00, c00, zx, y0, y1, LDS);
    return;
  }
  if (b <= 2) {
    rmid_run<2, 1>(b - 1, t, Wih1, Whh1, bih1, bhh1, h01, c01, y0, y1, y2, LDS);
    return;
  }
  if (b <= 6) {
    rmid_run<4, 2>(b - 3, t, Wih2, Whh2, bih2, bhh2, h02, c02, y1, y2, prog, LDS);
    return;
  }
  // R3 candidates: claim one of 4 quarter-roles on THIS block's XCD
  if (t == 0) {
    unsigned xcc;
    asm volatile("s_getreg_b32 %0, hwreg(HW_REG_XCC_ID)" : "=s"(xcc));
    xcc &= 7u;
    u32 r = atomicAdd(cnt + xcc, 1u);
    role = (r < 4u) ? (int)(xcc * 4u + r) : -1;
  }
  __syncthreads();
  const int ro = role;
  if (ro >= 0)
    r3_run(ro >> 2, ro & 3, t, Wih3, Whh3, bih3, bhh3, h03, c03, y2, hx, prog,
           cnt + 8, out, LDS);
  else
    keeper_run(t, cnt + 8, LDS);
}

extern "C" void kernel_launch(void* const* d_in, const int* in_sizes, int n_in,
                              void* d_out, int out_size, void* d_ws, size_t ws_size,
                              hipStream_t stream) {
  const float* x    = (const float*)d_in[0];
  const float* Wih0 = (const float*)d_in[1];
  const float* Whh0 = (const float*)d_in[2];
  const float* bih0 = (const float*)d_in[3];
  const float* bhh0 = (const float*)d_in[4];
  const float* h00  = (const float*)d_in[5];
  const float* c00  = (const float*)d_in[6];
  const float* Wih1 = (const float*)d_in[7];
  const float* Whh1 = (const float*)d_in[8];
  const float* bih1 = (const float*)d_in[9];
  const float* bhh1 = (const float*)d_in[10];
  const float* h01  = (const float*)d_in[11];
  const float* c01  = (const float*)d_in[12];
  const float* Wih2 = (const float*)d_in[13];
  const float* Whh2 = (const float*)d_in[14];
  const float* bih2 = (const float*)d_in[15];
  const float* bhh2 = (const float*)d_in[16];
  const float* h02  = (const float*)d_in[17];
  const float* c02  = (const float*)d_in[18];
  const float* Wih3 = (const float*)d_in[19];
  const float* Whh3 = (const float*)d_in[20];
  const float* bih3 = (const float*)d_in[21];
  const float* bhh3 = (const float*)d_in[22];
  const float* h03  = (const float*)d_in[23];
  const float* c03  = (const float*)d_in[24];

  float* ws = (float*)d_ws;
  float* out = (float*)d_out;
  u32* cnt = (u32*)(ws + ZX_FLOATS) + CNT_OFF;

  hipMemsetAsync(cnt, 0, 64, stream);  // zero claim counters + done counter
  zx0_kernel<<<512, 256, 0, stream>>>(x, Wih0, bih0, bhh0, ws);
  drnn_kernel<<<256, 256, 0, stream>>>(Whh0, h00, c00,
                                       Wih1, Whh1, bih1, bhh1, h01, c01,
                                       Wih2, Whh2, bih2, bhh2, h02, c02,
                                       Wih3, Whh3, bih3, bhh3, h03, c03,
                                       ws, out);
}